// Round 1
// 5590.059 us; speedup vs baseline: 2.4253x; 2.4253x over previous
//
#include <hip/hip_runtime.h>
#include <math.h>
#include <stdint.h>

// Problem constants (from reference)
constexpr int L  = 12;
constexpr int H  = 12;
constexpr int D  = 768;
constexpr int V  = 50257;
constexpr int DH = 64;
constexpr int B  = 4;
constexpr int TV = 64;
constexpr int TT = 448;
constexpr int T  = TV + TT;   // 512
constexpr int M  = B * T;     // 2048 rows in the token dimension

using bf16x8 = __attribute__((ext_vector_type(8))) __bf16;
using f32x4  = __attribute__((ext_vector_type(4))) float;

// Split-bf16 helpers: x = hi + lo, |x - hi - lo| <= 2^-16 |x| (truncation split).
__device__ __forceinline__ ushort bfhi(float x) { return (ushort)(__float_as_uint(x) >> 16); }
__device__ __forceinline__ float  bfup(ushort h) { return __uint_as_float(((unsigned)h) << 16); }

__device__ __forceinline__ float gelu_exact(float v) {
    return 0.5f * v * (1.0f + erff(v * 0.7071067811865476f));
}

// Async global -> LDS, 16 B per lane. LDS dest is wave-uniform base + lane*16.
__device__ __forceinline__ void gload16(const void* g, void* l) {
    __builtin_amdgcn_global_load_lds(
        (const __attribute__((address_space(1))) unsigned int*)(uintptr_t)g,
        (__attribute__((address_space(3))) unsigned int*)(uintptr_t)l,
        16, 0, 0);
}

// ---------------------------------------------------------------------------
// Embedding: h[b,t,:] = (t<TV ? visual[b,t,:] : wte[x[b,t-TV],:]) + wpe[t,:]
// ---------------------------------------------------------------------------
__global__ __launch_bounds__(256) void embed_kernel(
    const int* __restrict__ x, const float* __restrict__ vis,
    const float* __restrict__ wte, const float* __restrict__ wpe,
    float* __restrict__ h)
{
    const int row = blockIdx.x;          // b*T + t
    const int b = row / T, t = row % T;
    const float* src;
    if (t < TV) src = vis + ((size_t)b * TV + t) * D;
    else        src = wte + (size_t)x[b * TT + (t - TV)] * D;
    const float* pe = wpe + (size_t)t * D;
    float* dst = h + (size_t)row * D;
    for (int i = threadIdx.x; i < D; i += blockDim.x)
        dst[i] = src[i] + pe[i];
}

// ---------------------------------------------------------------------------
// LayerNorm over last dim (D=768). One block (256 thr) per row.
// Writes split-bf16 planes (hi/lo) consumed directly as MFMA A-operand.
// ---------------------------------------------------------------------------
__global__ __launch_bounds__(256) void ln_kernel(
    const float* __restrict__ in, const float* __restrict__ w,
    const float* __restrict__ bb, ushort* __restrict__ ohi,
    ushort* __restrict__ olo)
{
    const int row = blockIdx.x;
    const float* xr = in + (size_t)row * D;
    float s = 0.f, s2 = 0.f;
    for (int i = threadIdx.x; i < D; i += blockDim.x) {
        float v = xr[i];
        s += v; s2 += v * v;
    }
    #pragma unroll
    for (int off = 32; off; off >>= 1) {
        s  += __shfl_down(s,  off);
        s2 += __shfl_down(s2, off);
    }
    __shared__ float ls[4], ls2[4];
    const int wid = threadIdx.x >> 6, lane = threadIdx.x & 63;
    if (lane == 0) { ls[wid] = s; ls2[wid] = s2; }
    __syncthreads();
    if (threadIdx.x == 0) {
        float a = 0.f, c = 0.f;
        for (int i = 0; i < 4; ++i) { a += ls[i]; c += ls2[i]; }
        ls[0] = a; ls2[0] = c;
    }
    __syncthreads();
    const float mean = ls[0] / D;
    const float var  = ls2[0] / D - mean * mean;
    const float inv  = rsqrtf(var + 1e-5f);
    ushort* oh = ohi + (size_t)row * D;
    ushort* ol = olo + (size_t)row * D;
    for (int i = threadIdx.x; i < D; i += blockDim.x) {
        const float y = (xr[i] - mean) * inv * w[i] + bb[i];
        const ushort hh = bfhi(y);
        oh[i] = hh;
        ol[i] = bfhi(y - bfup(hh));
    }
}

// ---------------------------------------------------------------------------
// Weight convert + transpose: W f32 [K,N] -> Phi/Plo bf16 [N,K].
// ---------------------------------------------------------------------------
__global__ __launch_bounds__(256) void wconv_t(
    const float* __restrict__ W, ushort* __restrict__ Phi,
    ushort* __restrict__ Plo, int K, int N)
{
    __shared__ float tbuf[32][33];
    const int n0 = blockIdx.x * 32, k0 = blockIdx.y * 32;
    const int tx = threadIdx.x & 31, ty = threadIdx.x >> 5;   // ty 0..7
    for (int r = ty; r < 32; r += 8)
        tbuf[r][tx] = W[(size_t)(k0 + r) * N + n0 + tx];
    __syncthreads();
    for (int r = ty; r < 32; r += 8) {
        const float v = tbuf[tx][r];                 // = W[k0+tx][n0+r]
        const ushort hh = bfhi(v);
        const size_t idx = (size_t)(n0 + r) * K + k0 + tx;
        Phi[idx] = hh;
        Plo[idx] = bfhi(v - bfup(hh));
    }
}

// ---------------------------------------------------------------------------
// Split-bf16 MFMA GEMM:  C[M,N] = epi(A[M,K] @ B^T + bias) (+res)
//   A given as hi/lo bf16 planes [M,K]; B as hi/lo planes [N,K] (pre-split)
//   or, if BCONV, as f32 [N,K] converted in-kernel (head GEMM over wte).
//   3-pass accumulation: Ahi*Bhi + Ahi*Blo + Alo*Bhi  (f32 MFMA accum).
//   Tile 128x128, BK=64, 256 threads (4 waves, 2x2 of 64x64), LDS 64 KB.
//   LDS rows are 128 B with 16B-slot XOR swizzle (slot ^= row&7):
//   ds_read_b128 fragment reads are 2-way (free); staging pre-swizzles the
//   GLOBAL source address so global_load_lds keeps a linear LDS dest.
// ---------------------------------------------------------------------------
template<int OUTM, bool DOGELU, bool DORES, bool BCONV>
__global__ __launch_bounds__(256, 2) void gemm_mfma(
    const ushort* __restrict__ Ahi, const ushort* __restrict__ Alo,
    const ushort* __restrict__ Bhi, const ushort* __restrict__ Blo,
    const float* __restrict__ Bf32, const float* __restrict__ bias,
    const float* res, float* Cf, ushort* Chi, ushort* Clo,
    int N, int K)
{
    __shared__ ushort lds[4][128][64];   // planes: Ahi, Alo, Bhi, Blo
    const int tid  = threadIdx.x;
    const int wave = tid >> 6, lane = tid & 63;
    const int rl = lane & 15, g = lane >> 4;
    const int wm = wave >> 1, wn = wave & 1;
    const int bm = blockIdx.y * 128;
    const int bn = blockIdx.x * 128;

    // Staging geometry: dest chunk (wave*4+j)*1024B, lane covers 16B.
    // dest row = wave*32 + j*8 + (lane>>3), dest slot = lane&7,
    // source slot = dest slot ^ (row&7)  (involution).
    const int srow  = wave * 32 + (lane >> 3);
    const int sslot = (lane & 7) ^ (lane >> 3);
    // BCONV staging: 2 threads per B-row, 32 f32 each.
    const int brow = tid >> 1, bhalf = tid & 1;
    const int gnB  = bn + brow;

    f32x4 acc[4][4] = {};

    for (int k0 = 0; k0 < K; k0 += 64) {
        #pragma unroll
        for (int j = 0; j < 4; ++j) {
            const size_t gro = (size_t)(bm + srow + j * 8) * K + k0 + sslot * 8;
            gload16(Ahi + gro, &lds[0][0][0] + (wave * 4 + j) * 512);
            gload16(Alo + gro, &lds[1][0][0] + (wave * 4 + j) * 512);
        }
        if constexpr (!BCONV) {
            #pragma unroll
            for (int j = 0; j < 4; ++j) {
                const size_t gro = (size_t)(bn + srow + j * 8) * K + k0 + sslot * 8;
                gload16(Bhi + gro, &lds[2][0][0] + (wave * 4 + j) * 512);
                gload16(Blo + gro, &lds[3][0][0] + (wave * 4 + j) * 512);
            }
        } else {
            const bool bok = gnB < N;
            const float* bsrc = Bf32 + (size_t)gnB * K + k0 + bhalf * 32;
            #pragma unroll
            for (int i = 0; i < 8; ++i) {
                float4 v = bok ? *reinterpret_cast<const float4*>(bsrc + i * 4)
                               : make_float4(0.f, 0.f, 0.f, 0.f);
                ushort4 hv, lv;
                hv.x = bfhi(v.x); lv.x = bfhi(v.x - bfup(hv.x));
                hv.y = bfhi(v.y); lv.y = bfhi(v.y - bfup(hv.y));
                hv.z = bfhi(v.z); lv.z = bfhi(v.z - bfup(hv.z));
                hv.w = bfhi(v.w); lv.w = bfhi(v.w - bfup(hv.w));
                const int slot = bhalf * 4 + (i >> 1);
                const int doff = brow * 64 + ((slot ^ (brow & 7)) << 3) + (i & 1) * 4;
                *reinterpret_cast<ushort4*>(&lds[2][0][0] + doff) = hv;
                *reinterpret_cast<ushort4*>(&lds[3][0][0] + doff) = lv;
            }
        }
        __syncthreads();   // compiler drains vmcnt+lgkmcnt before s_barrier

        #pragma unroll
        for (int c = 0; c < 2; ++c) {
            bf16x8 aH[4], aL[4], bH[4], bL[4];
            const int sx = ((((c << 2) + g) ^ (rl & 7)) << 3);  // ushort offset
            #pragma unroll
            for (int f = 0; f < 4; ++f) {
                const int mr = wm * 64 + f * 16 + rl;
                const int nr = wn * 64 + f * 16 + rl;
                aH[f] = *reinterpret_cast<const bf16x8*>(&lds[0][mr][0] + sx);
                aL[f] = *reinterpret_cast<const bf16x8*>(&lds[1][mr][0] + sx);
                bH[f] = *reinterpret_cast<const bf16x8*>(&lds[2][nr][0] + sx);
                bL[f] = *reinterpret_cast<const bf16x8*>(&lds[3][nr][0] + sx);
            }
            #pragma unroll
            for (int i = 0; i < 4; ++i)
                #pragma unroll
                for (int j = 0; j < 4; ++j) {
                    acc[i][j] = __builtin_amdgcn_mfma_f32_16x16x32_bf16(aH[i], bH[j], acc[i][j], 0, 0, 0);
                    acc[i][j] = __builtin_amdgcn_mfma_f32_16x16x32_bf16(aH[i], bL[j], acc[i][j], 0, 0, 0);
                    acc[i][j] = __builtin_amdgcn_mfma_f32_16x16x32_bf16(aL[i], bH[j], acc[i][j], 0, 0, 0);
                }
        }
        __syncthreads();
    }

    // Epilogue. C/D layout (verified m89/m91): col = lane&15, row = (lane>>4)*4 + reg.
    #pragma unroll
    for (int j = 0; j < 4; ++j) {
        const int ncol = bn + wn * 64 + j * 16 + rl;
        if (BCONV && ncol >= N) continue;
        const float bj = bias ? bias[ncol] : 0.f;
        #pragma unroll
        for (int i = 0; i < 4; ++i) {
            const int mrow = bm + wm * 64 + i * 16 + g * 4;
            #pragma unroll
            for (int r = 0; r < 4; ++r) {
                float v = acc[i][j][r] + bj;
                if (DOGELU) v = gelu_exact(v);
                const size_t idx = (size_t)(mrow + r) * N + ncol;
                if (DORES) v += res[idx];
                if (OUTM == 0) {
                    Cf[idx] = v;
                } else {
                    const ushort hh = bfhi(v);
                    Chi[idx] = hh;
                    Clo[idx] = bfhi(v - bfup(hh));
                }
            }
        }
    }
}

// ---------------------------------------------------------------------------
// Attention scores: att[bh,q,k] = 0.125 * dot(Q[q], K[k]) + (k<=q ? 1 : 0)
// ---------------------------------------------------------------------------
__global__ __launch_bounds__(256) void attn_scores_kernel(
    const float* __restrict__ qkv, float* __restrict__ att)
{
    const int bh = blockIdx.z;
    const int b = bh / H, hh = bh % H;
    const int bq = blockIdx.y * 64;
    const int bk = blockIdx.x * 64;
    const float* Q  = qkv + (size_t)b * T * 3 * D + hh * DH;
    const float* Kp = Q + D;

    __shared__ float Qs[16][65];
    __shared__ float Ks[16][65];
    const int tid = threadIdx.x;
    const int tx = tid & 15, ty = tid >> 4;
    const int r  = tid >> 2;          // 0..63
    const int d4 = (tid & 3) << 2;    // 0,4,8,12

    float acc[4][4] = {};

    for (int k0 = 0; k0 < DH; k0 += 16) {
        {
            float4 v = *reinterpret_cast<const float4*>(&Q[(size_t)(bq + r) * 3 * D + k0 + d4]);
            Qs[d4 + 0][r] = v.x; Qs[d4 + 1][r] = v.y;
            Qs[d4 + 2][r] = v.z; Qs[d4 + 3][r] = v.w;
        }
        {
            float4 v = *reinterpret_cast<const float4*>(&Kp[(size_t)(bk + r) * 3 * D + k0 + d4]);
            Ks[d4 + 0][r] = v.x; Ks[d4 + 1][r] = v.y;
            Ks[d4 + 2][r] = v.z; Ks[d4 + 3][r] = v.w;
        }
        __syncthreads();
        #pragma unroll
        for (int kk = 0; kk < 16; ++kk) {
            float a[4], b2[4];
            #pragma unroll
            for (int i = 0; i < 4; ++i) a[i]  = Qs[kk][ty * 4 + i];
            #pragma unroll
            for (int j = 0; j < 4; ++j) b2[j] = Ks[kk][tx * 4 + j];
            #pragma unroll
            for (int i = 0; i < 4; ++i)
                #pragma unroll
                for (int j = 0; j < 4; ++j)
                    acc[i][j] = fmaf(a[i], b2[j], acc[i][j]);
        }
        __syncthreads();
    }

    #pragma unroll
    for (int i = 0; i < 4; ++i) {
        const int q = bq + ty * 4 + i;
        #pragma unroll
        for (int j = 0; j < 4; ++j) {
            const int k = bk + tx * 4 + j;
            att[((size_t)bh * T + q) * T + k] =
                acc[i][j] * 0.125f + (k <= q ? 1.0f : 0.0f);
        }
    }
}

// ---------------------------------------------------------------------------
// Softmax over rows of length T=512. One wave per row.
// ---------------------------------------------------------------------------
__global__ __launch_bounds__(64) void softmax_kernel(float* __restrict__ att)
{
    float* row = att + (size_t)blockIdx.x * T;
    const int lane = threadIdx.x;
    float v[8];
    float mx = -1e30f;
    #pragma unroll
    for (int i = 0; i < 8; ++i) { v[i] = row[lane + i * 64]; mx = fmaxf(mx, v[i]); }
    #pragma unroll
    for (int off = 32; off; off >>= 1) mx = fmaxf(mx, __shfl_xor(mx, off));
    float s = 0.f;
    #pragma unroll
    for (int i = 0; i < 8; ++i) { v[i] = __expf(v[i] - mx); s += v[i]; }
    #pragma unroll
    for (int off = 32; off; off >>= 1) s += __shfl_xor(s, off);
    const float inv = 1.0f / s;
    #pragma unroll
    for (int i = 0; i < 8; ++i) row[lane + i * 64] = v[i] * inv;
}

// ---------------------------------------------------------------------------
// PV: o[b,q,hh*DH+d] = sum_k att[bh,q,k] * V[b,k,hh*DH+d]; writes split planes.
// ---------------------------------------------------------------------------
__global__ __launch_bounds__(256) void attn_pv_kernel(
    const float* __restrict__ att, const float* __restrict__ qkv,
    ushort* __restrict__ o_hi, ushort* __restrict__ o_lo)
{
    const int bh = blockIdx.z;
    const int b = bh / H, hh = bh % H;
    const int bq = blockIdx.y * 64;
    const float* Vp = qkv + (size_t)b * T * 3 * D + 2 * D + hh * DH;
    const float* Am = att + (size_t)bh * T * T;

    __shared__ float As[16][65];
    __shared__ float Vs[16][65];
    const int tid = threadIdx.x;
    const int tx = tid & 15, ty = tid >> 4;
    const int r  = tid >> 2;
    const int k4 = (tid & 3) << 2;

    float acc[4][4] = {};

    for (int k0 = 0; k0 < T; k0 += 16) {
        {
            float4 v = *reinterpret_cast<const float4*>(&Am[(size_t)(bq + r) * T + k0 + k4]);
            As[k4 + 0][r] = v.x; As[k4 + 1][r] = v.y;
            As[k4 + 2][r] = v.z; As[k4 + 3][r] = v.w;
        }
        {
            const int kk = tid >> 4;          // 0..15
            const int dd = (tid & 15) << 2;   // 0..60
            float4 v = *reinterpret_cast<const float4*>(&Vp[(size_t)(k0 + kk) * 3 * D + dd]);
            Vs[kk][dd + 0] = v.x; Vs[kk][dd + 1] = v.y;
            Vs[kk][dd + 2] = v.z; Vs[kk][dd + 3] = v.w;
        }
        __syncthreads();
        #pragma unroll
        for (int kk = 0; kk < 16; ++kk) {
            float a[4], b2[4];
            #pragma unroll
            for (int i = 0; i < 4; ++i) a[i]  = As[kk][ty * 4 + i];
            #pragma unroll
            for (int j = 0; j < 4; ++j) b2[j] = Vs[kk][tx * 4 + j];
            #pragma unroll
            for (int i = 0; i < 4; ++i)
                #pragma unroll
                for (int j = 0; j < 4; ++j)
                    acc[i][j] = fmaf(a[i], b2[j], acc[i][j]);
        }
        __syncthreads();
    }

    #pragma unroll
    for (int i = 0; i < 4; ++i) {
        const int q = bq + ty * 4 + i;
        #pragma unroll
        for (int j = 0; j < 4; ++j) {
            const int d = tx * 4 + j;
            const size_t idx = ((size_t)b * T + q) * D + hh * DH + d;
            const float v = acc[i][j];
            const ushort uh = bfhi(v);
            o_hi[idx] = uh;
            o_lo[idx] = bfhi(v - bfup(uh));
        }
    }
}

// ---------------------------------------------------------------------------
// Launch
// ---------------------------------------------------------------------------
extern "C" void kernel_launch(void* const* d_in, const int* in_sizes, int n_in,
                              void* d_out, int out_size, void* d_ws, size_t ws_size,
                              hipStream_t stream)
{
    const int*   x      = (const int*)  d_in[0];
    const float* vis    = (const float*)d_in[1];
    const float* wte    = (const float*)d_in[2];
    const float* wpe    = (const float*)d_in[3];
    const float* ln1_w  = (const float*)d_in[4];
    const float* ln1_b  = (const float*)d_in[5];
    const float* attn_w = (const float*)d_in[6];
    const float* attn_b = (const float*)d_in[7];
    const float* proj_w = (const float*)d_in[8];
    const float* proj_b = (const float*)d_in[9];
    const float* ln2_w  = (const float*)d_in[10];
    const float* ln2_b  = (const float*)d_in[11];
    const float* fc_w   = (const float*)d_in[12];
    const float* fc_b   = (const float*)d_in[13];
    const float* fc2_w  = (const float*)d_in[14];
    const float* fc2_b  = (const float*)d_in[15];
    const float* lnf_w  = (const float*)d_in[16];
    const float* lnf_b  = (const float*)d_in[17];

    float* out = (float*)d_out;

    // ws (12.58 MB): h f32 + n hi/lo planes (survive until the head GEMM).
    float*  h    = (float*)d_ws;
    ushort* n_hi = (ushort*)(h + (size_t)M * D);
    ushort* n_lo = n_hi + (size_t)M * D;

    // Scratch carved from d_out (out only written by the final head GEMM):
    // qkv 4.72M + att 12.58M f32, then ushort planes; total ~32.2M f32 << 102.9M.
    float* qkv = out;
    float* att = qkv + (size_t)M * 3 * D;
    ushort* o_hi   = (ushort*)(att + (size_t)B * H * T * T);
    ushort* o_lo   = o_hi   + (size_t)M * D;
    ushort* mid_hi = o_lo   + (size_t)M * D;
    ushort* mid_lo = mid_hi + (size_t)M * 4 * D;
    ushort* wq_hi  = mid_lo + (size_t)M * 4 * D;
    ushort* wq_lo  = wq_hi  + (size_t)D * 3 * D;
    ushort* wp_hi  = wq_lo  + (size_t)D * 3 * D;
    ushort* wp_lo  = wp_hi  + (size_t)D * D;
    ushort* wf_hi  = wp_lo  + (size_t)D * D;
    ushort* wf_lo  = wf_hi  + (size_t)D * 4 * D;
    ushort* wf2_hi = wf_lo  + (size_t)D * 4 * D;
    ushort* wf2_lo = wf2_hi + (size_t)4 * D * D;

    embed_kernel<<<M, 256, 0, stream>>>(x, vis, wte, wpe, h);

    for (int l = 0; l < L; ++l) {
        ln_kernel<<<M, 256, 0, stream>>>(h, ln1_w + (size_t)l * D, ln1_b + (size_t)l * D,
                                         n_hi, n_lo);

        wconv_t<<<dim3(3 * D / 32, D / 32), 256, 0, stream>>>(
            attn_w + (size_t)l * D * 3 * D, wq_hi, wq_lo, D, 3 * D);
        gemm_mfma<0, false, false, false><<<dim3(3 * D / 128, M / 128), 256, 0, stream>>>(
            n_hi, n_lo, wq_hi, wq_lo, nullptr, attn_b + (size_t)l * 3 * D,
            nullptr, qkv, nullptr, nullptr, 3 * D, D);

        attn_scores_kernel<<<dim3(T / 64, T / 64, B * H), 256, 0, stream>>>(qkv, att);
        softmax_kernel<<<B * H * T, 64, 0, stream>>>(att);
        attn_pv_kernel<<<dim3(1, T / 64, B * H), 256, 0, stream>>>(att, qkv, o_hi, o_lo);

        wconv_t<<<dim3(D / 32, D / 32), 256, 0, stream>>>(
            proj_w + (size_t)l * D * D, wp_hi, wp_lo, D, D);
        gemm_mfma<0, false, true, false><<<dim3(D / 128, M / 128), 256, 0, stream>>>(
            o_hi, o_lo, wp_hi, wp_lo, nullptr, proj_b + (size_t)l * D,
            h, h, nullptr, nullptr, D, D);

        ln_kernel<<<M, 256, 0, stream>>>(h, ln2_w + (size_t)l * D, ln2_b + (size_t)l * D,
                                         n_hi, n_lo);

        wconv_t<<<dim3(4 * D / 32, D / 32), 256, 0, stream>>>(
            fc_w + (size_t)l * D * 4 * D, wf_hi, wf_lo, D, 4 * D);
        gemm_mfma<1, true, false, false><<<dim3(4 * D / 128, M / 128), 256, 0, stream>>>(
            n_hi, n_lo, wf_hi, wf_lo, nullptr, fc_b + (size_t)l * 4 * D,
            nullptr, nullptr, mid_hi, mid_lo, 4 * D, D);

        wconv_t<<<dim3(D / 32, 4 * D / 32), 256, 0, stream>>>(
            fc2_w + (size_t)l * 4 * D * D, wf2_hi, wf2_lo, 4 * D, D);
        gemm_mfma<0, false, true, false><<<dim3(D / 128, M / 128), 256, 0, stream>>>(
            mid_hi, mid_lo, wf2_hi, wf2_lo, nullptr, fc2_b + (size_t)l * D,
            h, h, nullptr, nullptr, D, 4 * D);
    }

    ln_kernel<<<M, 256, 0, stream>>>(h, lnf_w, lnf_b, n_hi, n_lo);

    // Tied-embedding head: C[m,v] = sum_k n[m,k] * wte[v,k]; wte converted in-kernel.
    gemm_mfma<0, false, false, true><<<dim3((V + 127) / 128, M / 128), 256, 0, stream>>>(
        n_hi, n_lo, nullptr, nullptr, wte, nullptr,
        nullptr, out, nullptr, nullptr, V, D);
}